// Round 3
// baseline (296.369 us; speedup 1.0000x reference)
//
#include <hip/hip_runtime.h>

#define CH 256
#define KK 4
#define HW 64
#define PLANE 4096      // 64*64
#define TS 67           // LDS tile row stride (66 logical cols + 1 pad -> conflict-free banks)

typedef float fx4 __attribute__((ext_vector_type(4)));   // clang-native vec4 (nontemporal-store OK)

// ---------------- Kernel 1: global average pool per (b,c) plane ----------------
__global__ __launch_bounds__(256) void gap_kernel(const float* __restrict__ x,
                                                  float* __restrict__ g) {
    int plane = blockIdx.x;                       // b*CH + c
    const float4* p = (const float4*)(x + (size_t)plane * PLANE);
    float sum = 0.f;
    #pragma unroll
    for (int k = 0; k < 4; ++k) {
        float4 v = p[threadIdx.x + k * 256];
        sum += (v.x + v.y) + (v.z + v.w);
    }
    for (int off = 32; off > 0; off >>= 1)
        sum += __shfl_down(sum, off);
    __shared__ float ws[4];
    int lane = threadIdx.x & 63;
    int wid  = threadIdx.x >> 6;
    if (lane == 0) ws[wid] = sum;
    __syncthreads();
    if (threadIdx.x == 0)
        g[plane] = (ws[0] + ws[1] + ws[2] + ws[3]) * (1.f / PLANE);
}

// ---------------- Kernel 2: depthwise 3x3 conv, attention MLP fused per-block ----------------
// The attn MLP (fc1->relu->fc2->softmax over K=4) is recomputed redundantly by every
// block from g[b,:] (stream-ordered visible after gap_kernel). Cost: 16K FMA + 64 KB
// fc1_w L2-reads per block (~15 us aggregate L2 BW, hidden under the HBM/L3-bound conv);
// saves the whole-GPU serialization bubble of a 32x64-thread attn dispatch.
// tile[r*TS + c] holds input pixel (r-1, c-1); logical tile 66 rows x 66 cols.
__global__ __launch_bounds__(256) void dwconv_kernel(const float* __restrict__ x,
                              const float* __restrict__ g,
                              const float* __restrict__ conv_w,
                              const float* __restrict__ fc1_w, const float* __restrict__ fc1_b,
                              const float* __restrict__ fc2_w, const float* __restrict__ fc2_b,
                              float* __restrict__ out) {
    int plane = blockIdx.x;                       // b*CH + c
    int b = plane >> 8;
    int c = plane & (CH - 1);
    __shared__ float tile[66 * TS];
    __shared__ float gs[CH];
    __shared__ float red[256];
    __shared__ float h[64];
    __shared__ float logit[KK];
    int t = threadIdx.x;

    // ---- issue x loads into registers FIRST: HBM/L3 latency hides under the MLP ----
    const float4* xp4 = (const float4*)(x + (size_t)plane * PLANE);
    float4 v0 = xp4[t], v1 = xp4[t + 256], v2 = xp4[t + 512], v3 = xp4[t + 768];

    // ---- stage g[b,:] for the MLP ----
    gs[t] = g[b * CH + t];

    // ---- zero halo (260 cells): top row, bottom row, left col, right col ----
    for (int i = t; i < 260; i += 256) {
        int idx;
        if (i < 66)       idx = i;                       // top row r=0, c=i
        else if (i < 132) idx = 65 * TS + (i - 66);      // bottom row r=65
        else if (i < 196) idx = (i - 131) * TS;          // left col c=0, r=1..64
        else              idx = (i - 195) * TS + 65;     // right col c=65, r=1..64
        tile[idx] = 0.f;
    }
    __syncthreads();                              // gs ready

    // ---- fc1 (64 x 256) + relu: 4-way split-K across 256 threads (verified R1 code) ----
    {
        int o = t & 63, pq = t >> 6;
        const float4* wr = (const float4*)(fc1_w + o * CH + pq * 64);
        const float4* gv = (const float4*)(gs + pq * 64);
        float a0 = 0.f, a1 = 0.f, a2 = 0.f, a3 = 0.f;
        #pragma unroll
        for (int i = 0; i < 16; ++i) {
            float4 w4 = wr[i], g4 = gv[i];
            a0 = fmaf(w4.x, g4.x, a0);
            a1 = fmaf(w4.y, g4.y, a1);
            a2 = fmaf(w4.z, g4.z, a2);
            a3 = fmaf(w4.w, g4.w, a3);
        }
        red[t] = (a0 + a1) + (a2 + a3);
    }
    __syncthreads();
    if (t < 64)
        h[t] = fmaxf(red[t] + red[64 + t] + red[128 + t] + red[192 + t] + fc1_b[t], 0.f);
    __syncthreads();
    if (t < KK) {
        const float4* w2 = (const float4*)(fc2_w + t * 64);
        const float4* hv = (const float4*)h;
        float a0 = fc2_b[t], a1 = 0.f, a2 = 0.f, a3 = 0.f;
        #pragma unroll
        for (int i = 0; i < 16; ++i) {
            float4 w4 = w2[i], h4 = hv[i];
            a0 = fmaf(w4.x, h4.x, a0);
            a1 = fmaf(w4.y, h4.y, a1);
            a2 = fmaf(w4.z, h4.z, a2);
            a3 = fmaf(w4.w, h4.w, a3);
        }
        logit[t] = (a0 + a1) + (a2 + a3);
    }
    __syncthreads();

    // ---- softmax over K=4, computed redundantly by every thread (registers) ----
    float m  = fmaxf(fmaxf(logit[0], logit[1]), fmaxf(logit[2], logit[3]));
    float e0 = __expf(logit[0] - m), e1 = __expf(logit[1] - m),
          e2 = __expf(logit[2] - m), e3 = __expf(logit[3] - m);
    float inv = 1.f / (e0 + e1 + e2 + e3);
    float a0 = e0 * inv, a1 = e1 * inv, a2 = e2 * inv, a3 = e3 * inv;

    // ---- commit staged x registers to the LDS tile ----
    #pragma unroll
    for (int k = 0; k < 4; ++k) {
        int idx = t + k * 256;                    // 0..1023
        int y   = idx >> 4;                       // 0..63
        int xq  = (idx & 15) << 2;                // 0,4,...,60
        float4 v = (k == 0) ? v0 : (k == 1) ? v1 : (k == 2) ? v2 : v3;
        float* d = &tile[(y + 1) * TS + 1 + xq];
        d[0] = v.x; d[1] = v.y; d[2] = v.z; d[3] = v.w;
    }

    // ---- effective 3x3 kernel = attn-weighted sum of K kernels (linearity) ----
    float w[9];
    #pragma unroll
    for (int j = 0; j < 9; ++j) {
        w[j] = a0 * conv_w[(0 * CH + c) * 9 + j]
             + a1 * conv_w[(1 * CH + c) * 9 + j]
             + a2 * conv_w[(2 * CH + c) * 9 + j]
             + a3 * conv_w[(3 * CH + c) * 9 + j];
    }
    __syncthreads();

    // ---- compute: each thread does 4 adjacent pixels x 4 row-groups ----
    int y0 = t >> 4;                              // 0..15
    int xq = (t & 15) << 2;                       // output col of first pixel
    fx4* op4 = (fx4*)(out + (size_t)plane * PLANE);
    #pragma unroll
    for (int gi = 0; gi < 4; ++gi) {
        int y = y0 + gi * 16;
        float s0 = 0.f, s1 = 0.f, s2 = 0.f, s3 = 0.f;
        #pragma unroll
        for (int dy = 0; dy < 3; ++dy) {
            const float* r = &tile[(y + dy) * TS + xq];
            float e0_ = r[0], e1_ = r[1], e2_ = r[2], e3_ = r[3], e4_ = r[4], e5_ = r[5];
            float w0 = w[dy * 3], w1 = w[dy * 3 + 1], w2 = w[dy * 3 + 2];
            s0 = fmaf(e0_, w0, fmaf(e1_, w1, fmaf(e2_, w2, s0)));
            s1 = fmaf(e1_, w0, fmaf(e2_, w1, fmaf(e3_, w2, s1)));
            s2 = fmaf(e2_, w0, fmaf(e3_, w1, fmaf(e4_, w2, s2)));
            s3 = fmaf(e3_, w0, fmaf(e4_, w1, fmaf(e5_, w2, s3)));
        }
        fx4 res = {s0, s1, s2, s3};
        __builtin_nontemporal_store(res, &op4[(y << 4) + (t & 15)]);
    }
}

extern "C" void kernel_launch(void* const* d_in, const int* in_sizes, int n_in,
                              void* d_out, int out_size, void* d_ws, size_t ws_size,
                              hipStream_t stream) {
    const float* x      = (const float*)d_in[0];
    const float* conv_w = (const float*)d_in[1];
    const float* fc1_w  = (const float*)d_in[2];
    const float* fc1_b  = (const float*)d_in[3];
    const float* fc2_w  = (const float*)d_in[4];
    const float* fc2_b  = (const float*)d_in[5];
    float* out = (float*)d_out;

    int B = in_sizes[0] / (CH * HW * HW);         // 32

    float* g = (float*)d_ws;                      // B*CH floats

    gap_kernel   <<<B * CH, 256, 0, stream>>>(x, g);
    dwconv_kernel<<<B * CH, 256, 0, stream>>>(x, g, conv_w, fc1_w, fc1_b, fc2_w, fc2_b, out);
}

// Round 4
// 262.431 us; speedup vs baseline: 1.1293x; 1.1293x over previous
//
#include <hip/hip_runtime.h>

#define CH 256
#define KK 4
#define HW 64
#define PLANE 4096      // 64*64

typedef float fx4 __attribute__((ext_vector_type(4)));   // clang-native vec4 (nontemporal-store OK)

// ---------------- Kernel 1: global average pool per (b,c) plane ----------------
__global__ __launch_bounds__(256) void gap_kernel(const float* __restrict__ x,
                                                  float* __restrict__ g) {
    int plane = blockIdx.x;                       // b*CH + c
    const float4* p = (const float4*)(x + (size_t)plane * PLANE);
    float sum = 0.f;
    #pragma unroll
    for (int k = 0; k < 4; ++k) {
        float4 v = p[threadIdx.x + k * 256];
        sum += (v.x + v.y) + (v.z + v.w);
    }
    for (int off = 32; off > 0; off >>= 1)
        sum += __shfl_down(sum, off);
    __shared__ float ws[4];
    int lane = threadIdx.x & 63;
    int wid  = threadIdx.x >> 6;
    if (lane == 0) ws[wid] = sum;
    __syncthreads();
    if (threadIdx.x == 0)
        g[plane] = (ws[0] + ws[1] + ws[2] + ws[3]) * (1.f / PLANE);
}

// ---------------- Kernel 2: attention MLP + softmax over K ----------------
__global__ __launch_bounds__(64) void attn_kernel(const float* __restrict__ g,
                            const float* __restrict__ fc1_w, const float* __restrict__ fc1_b,
                            const float* __restrict__ fc2_w, const float* __restrict__ fc2_b,
                            float* __restrict__ attn) {
    int b = blockIdx.x;
    int t = threadIdx.x;                          // 0..63, one wave
    __shared__ float gs[CH];
    __shared__ float h[64];
    __shared__ float logit[KK];
    for (int i = t; i < CH; i += 64) gs[i] = g[b * CH + i];
    __syncthreads();
    // fc1 (64 x 256) + relu — one output per thread, 4-way split accumulators
    {
        const float4* wr = (const float4*)(fc1_w + t * CH);
        const float4* gv = (const float4*)gs;
        float a0 = fc1_b[t], a1 = 0.f, a2 = 0.f, a3 = 0.f;
        #pragma unroll 4
        for (int i = 0; i < CH / 4; ++i) {
            float4 w4 = wr[i], g4 = gv[i];
            a0 = fmaf(w4.x, g4.x, a0);
            a1 = fmaf(w4.y, g4.y, a1);
            a2 = fmaf(w4.z, g4.z, a2);
            a3 = fmaf(w4.w, g4.w, a3);
        }
        h[t] = fmaxf((a0 + a1) + (a2 + a3), 0.f);
    }
    __syncthreads();
    if (t < KK) {
        const float4* w2 = (const float4*)(fc2_w + t * 64);
        const float4* hv = (const float4*)h;
        float a0 = fc2_b[t], a1 = 0.f, a2 = 0.f, a3 = 0.f;
        #pragma unroll
        for (int i = 0; i < 16; ++i) {
            float4 w4 = w2[i], h4 = hv[i];
            a0 = fmaf(w4.x, h4.x, a0);
            a1 = fmaf(w4.y, h4.y, a1);
            a2 = fmaf(w4.z, h4.z, a2);
            a3 = fmaf(w4.w, h4.w, a3);
        }
        logit[t] = (a0 + a1) + (a2 + a3);
    }
    __syncthreads();
    if (t == 0) {
        float m = fmaxf(fmaxf(logit[0], logit[1]), fmaxf(logit[2], logit[3]));
        float e[KK];
        float s = 0.f;
        #pragma unroll
        for (int k = 0; k < KK; ++k) { e[k] = __expf(logit[k] - m); s += e[k]; }
        float inv = 1.f / s;
        #pragma unroll
        for (int k = 0; k < KK; ++k) attn[b * KK + k] = e[k] * inv;
    }
}

// ---------------- Kernel 3: depthwise 3x3 conv, aligned-b128 LDS + shuffle halo ----------------
// LDS tile: linear float4 tile4[64*16] = x plane, no halo, no pad. All LDS traffic is
// 16B-aligned b128 on the linear (m134-optimal) bank pattern. Column halo (+/-1) via
// __shfl from adjacent lane; row halo via predicated zero load. Rolling 3-row window:
// each thread computes 4 CONSECUTIVE output rows -> only 6 row-loads per thread.
struct R6 { float e0, e1, e2, e3, e4, e5; };     // input cols xq-1 .. xq+4 of one row

__global__ __launch_bounds__(256) void dwconv_kernel(const float* __restrict__ x,
                              const float* __restrict__ conv_w,
                              const float* __restrict__ attn, float* __restrict__ out) {
    int plane = blockIdx.x;                       // b*CH + c
    int b = plane >> 8;
    int c = plane & (CH - 1);
    __shared__ float4 tile4[64 * 16];             // 16 KB, linear
    int t = threadIdx.x;

    // ---- issue x loads first: HBM/L3 latency hides under the weight combine ----
    const float4* xp4 = (const float4*)(x + (size_t)plane * PLANE);
    float4 v0 = xp4[t], v1 = xp4[t + 256], v2 = xp4[t + 512], v3 = xp4[t + 768];

    // ---- effective 3x3 kernel = attn-weighted sum of K kernels (linearity) ----
    float a0 = attn[b * KK + 0], a1 = attn[b * KK + 1],
          a2 = attn[b * KK + 2], a3 = attn[b * KK + 3];
    float w[9];
    #pragma unroll
    for (int j = 0; j < 9; ++j) {
        w[j] = a0 * conv_w[(0 * CH + c) * 9 + j]
             + a1 * conv_w[(1 * CH + c) * 9 + j]
             + a2 * conv_w[(2 * CH + c) * 9 + j]
             + a3 * conv_w[(3 * CH + c) * 9 + j];
    }

    // ---- commit to LDS: linear ds_write_b128, stride-1 lanes (conflict-free) ----
    tile4[t] = v0; tile4[t + 256] = v1; tile4[t + 512] = v2; tile4[t + 768] = v3;
    __syncthreads();

    int c4 = t & 15;                              // float4-column 0..15
    int ys = t >> 4;                              // row-strip 0..15
    int r0 = ys << 2;                             // first output row of this thread

    // row loader: aligned b128 read (predicated zero outside [0,64)), +/-1 col via shfl
    auto load_row = [&](int ry) -> R6 {
        float4 f = {0.f, 0.f, 0.f, 0.f};
        if ((unsigned)ry < 64u) f = tile4[(ry << 4) + c4];
        float lw = __shfl_up(f.w, 1);             // lane t-1's col xq-1
        float rx = __shfl_down(f.x, 1);           // lane t+1's col xq+4
        R6 r;
        r.e0 = (c4 == 0)  ? 0.f : lw;
        r.e1 = f.x; r.e2 = f.y; r.e3 = f.z; r.e4 = f.w;
        r.e5 = (c4 == 15) ? 0.f : rx;
        return r;
    };
    // identical FMA nesting/order to the verified R2 kernel -> bitwise-same results
    auto acc_row = [&](const R6& r, float w0, float w1, float w2,
                       float& s0, float& s1, float& s2, float& s3) {
        s0 = fmaf(r.e0, w0, fmaf(r.e1, w1, fmaf(r.e2, w2, s0)));
        s1 = fmaf(r.e1, w0, fmaf(r.e2, w1, fmaf(r.e3, w2, s1)));
        s2 = fmaf(r.e2, w0, fmaf(r.e3, w1, fmaf(r.e4, w2, s2)));
        s3 = fmaf(r.e3, w0, fmaf(r.e4, w1, fmaf(r.e5, w2, s3)));
    };

    R6 ra = load_row(r0 - 1);
    R6 rb = load_row(r0);
    R6 rc = load_row(r0 + 1);

    fx4* op4 = (fx4*)(out + (size_t)plane * PLANE);
    #pragma unroll
    for (int j = 0; j < 4; ++j) {
        float s0 = 0.f, s1 = 0.f, s2 = 0.f, s3 = 0.f;
        acc_row(ra, w[0], w[1], w[2], s0, s1, s2, s3);   // top row (dy=0)
        acc_row(rb, w[3], w[4], w[5], s0, s1, s2, s3);   // mid row (dy=1)
        acc_row(rc, w[6], w[7], w[8], s0, s1, s2, s3);   // bot row (dy=2)
        fx4 res = {s0, s1, s2, s3};
        __builtin_nontemporal_store(res, &op4[((r0 + j) << 4) + c4]);
        if (j < 3) {                              // roll the 3-row window down one row
            ra = rb; rb = rc; rc = load_row(r0 + 2 + j);
        }
    }
}

extern "C" void kernel_launch(void* const* d_in, const int* in_sizes, int n_in,
                              void* d_out, int out_size, void* d_ws, size_t ws_size,
                              hipStream_t stream) {
    const float* x      = (const float*)d_in[0];
    const float* conv_w = (const float*)d_in[1];
    const float* fc1_w  = (const float*)d_in[2];
    const float* fc1_b  = (const float*)d_in[3];
    const float* fc2_w  = (const float*)d_in[4];
    const float* fc2_b  = (const float*)d_in[5];
    float* out = (float*)d_out;

    int B = in_sizes[0] / (CH * HW * HW);         // 32

    float* g    = (float*)d_ws;                   // B*CH floats
    float* attn = g + B * CH;                     // B*KK floats

    gap_kernel <<<B * CH, 256, 0, stream>>>(x, g);
    attn_kernel<<<B, 64, 0, stream>>>(g, fc1_w, fc1_b, fc2_w, fc2_b, attn);
    dwconv_kernel<<<B * CH, 256, 0, stream>>>(x, conv_w, attn, out);
}